// Round 2
// baseline (235.264 us; speedup 1.0000x reference)
//
#include <hip/hip_runtime.h>
#include <hip/hip_bf16.h>
#include <math.h>

// Problem constants (B,D,N from reference)
#define MDIM 4096   // batch rows
#define KDIM 2048   // feature dim D
#define NDIM 4096   // output dim N
#define DT   0.01f
#define TWO_PI_F 6.283185307179586f
#define CH 64       // scan chunks
#define CL 64       // steps per chunk  (CH*CL == MDIM)

typedef __attribute__((ext_vector_type(8))) short bf16x8;
typedef __attribute__((ext_vector_type(4))) float f32x4;

__device__ __forceinline__ unsigned short f2bf(float f) {
  unsigned int u = __float_as_uint(f);
  u += 0x7FFFu + ((u >> 16) & 1u);           // round-to-nearest-even
  return (unsigned short)(u >> 16);
}
__device__ __forceinline__ float bf2f(unsigned short u) {
  return __uint_as_float(((unsigned int)u) << 16);
}

// ---------------- cast fp32 -> bf16 (vectorized x4) ----------------
__global__ void cast_bf16_kernel(const float* __restrict__ src,
                                 unsigned short* __restrict__ dst, int n4) {
  int i = blockIdx.x * blockDim.x + threadIdx.x;
  if (i >= n4) return;
  float4 v = ((const float4*)src)[i];
  ushort4 o;
  o.x = f2bf(v.x); o.y = f2bf(v.y); o.z = f2bf(v.z); o.w = f2bf(v.w);
  ((ushort4*)dst)[i] = o;
}

// ---------------- GEMM: force = x @ W^T + b, bf16 MFMA ----------------
// A: [MDIM][KDIM] bf16 row-major (x), Bm: [NDIM][KDIM] bf16 row-major (W)
// C: [MDIM][NDIM] bf16 (force). Tile 128x128, BK=32, 4 waves (2x2), each
// wave computes 64x64 via 4x4 grid of 16x16x32 MFMAs.
__global__ __launch_bounds__(256, 2) void gemm_bt_kernel(
    const unsigned short* __restrict__ A,
    const unsigned short* __restrict__ Bm,
    const float* __restrict__ bias,
    unsigned short* __restrict__ C) {
  __shared__ __align__(16) unsigned short sA[128 * 32];
  __shared__ __align__(16) unsigned short sB[128 * 32];

  const int tid  = threadIdx.x;
  const int lane = tid & 63;
  const int wave = tid >> 6;
  const int wr = wave >> 1;        // wave row (0..1) -> 64 rows
  const int wc = wave & 1;         // wave col (0..1) -> 64 cols
  const int q  = lane >> 4;        // quad 0..3
  const int lm = lane & 15;

  const int bM = blockIdx.x * 128;
  const int bN = blockIdx.y * 128;

  f32x4 acc[4][4];
#pragma unroll
  for (int i = 0; i < 4; i++)
#pragma unroll
    for (int j = 0; j < 4; j++) acc[i][j] = (f32x4){0.f, 0.f, 0.f, 0.f};

  // staging: 128x32 bf16 tile = 8KB = 512 x 16B; 256 threads -> 2 rounds
  const int idx0 = tid;            // covers rows 0..63
  const int idx1 = tid + 256;      // covers rows 64..127
  const int r0 = idx0 >> 2, c0 = (idx0 & 3) * 8;
  const int r1 = idx1 >> 2, c1 = (idx1 & 3) * 8;

  for (int k0 = 0; k0 < KDIM; k0 += 32) {
    uint4 av0 = *(const uint4*)&A [(size_t)(bM + r0) * KDIM + k0 + c0];
    uint4 av1 = *(const uint4*)&A [(size_t)(bM + r1) * KDIM + k0 + c1];
    uint4 bv0 = *(const uint4*)&Bm[(size_t)(bN + r0) * KDIM + k0 + c0];
    uint4 bv1 = *(const uint4*)&Bm[(size_t)(bN + r1) * KDIM + k0 + c1];
    __syncthreads();               // previous iter's LDS reads complete
    *(uint4*)&sA[idx0 * 8] = av0;
    *(uint4*)&sA[idx1 * 8] = av1;
    *(uint4*)&sB[idx0 * 8] = bv0;
    *(uint4*)&sB[idx1 * 8] = bv1;
    __syncthreads();               // LDS tile visible

    bf16x8 af[4], bfr[4];
#pragma unroll
    for (int mt = 0; mt < 4; mt++)
      af[mt]  = *(const bf16x8*)&sA[(wr * 64 + mt * 16 + lm) * 32 + q * 8];
#pragma unroll
    for (int nt = 0; nt < 4; nt++)
      bfr[nt] = *(const bf16x8*)&sB[(wc * 64 + nt * 16 + lm) * 32 + q * 8];

#pragma unroll
    for (int mt = 0; mt < 4; mt++)
#pragma unroll
      for (int nt = 0; nt < 4; nt++)
        acc[mt][nt] = __builtin_amdgcn_mfma_f32_16x16x32_bf16(
            af[mt], bfr[nt], acc[mt][nt], 0, 0, 0);
  }

  // epilogue: D layout col=lane&15, row=quad*4+reg (m89/m91-verified)
#pragma unroll
  for (int nt = 0; nt < 4; nt++) {
    const int col = bN + wc * 64 + nt * 16 + lm;
    const float bz = bias[col];
#pragma unroll
    for (int mt = 0; mt < 4; mt++) {
      const int row0 = bM + wr * 64 + mt * 16 + q * 4;
#pragma unroll
      for (int r = 0; r < 4; r++)
        C[(size_t)(row0 + r) * NDIM + col] = f2bf(acc[mt][nt][r] + bz);
    }
  }
}

// ---------------- scan pass 1: per-chunk partials (zero init) ----------------
__global__ void scan_pass1(const unsigned short* __restrict__ force,
                           const float* __restrict__ freq,
                           const float* __restrict__ damp,
                           float* __restrict__ chunkS,
                           float* __restrict__ chunkV) {
  int gid = blockIdx.x * blockDim.x + threadIdx.x;   // gid = c*NDIM + n
  int n = gid & (NDIM - 1);
  int c = gid >> 12;
  float om = TWO_PI_F * freq[n];
  float osq = om * om;
  float dp = damp[n];
  float s = 0.f, v = 0.f;
  const unsigned short* fp = force + (size_t)c * CL * NDIM + n;
#pragma unroll 8
  for (int i = 0; i < CL; i++) {
    float f = bf2f(fp[(size_t)i * NDIM]);
    float a = -osq * s - dp * v + f;
    v += a * DT;
    s += v * DT;
  }
  chunkS[gid] = s;
  chunkV[gid] = v;
}

// ---------------- scan pass 2: sequential combine over chunks ----------------
__global__ void scan_pass2(const float* __restrict__ chunkS,
                           const float* __restrict__ chunkV,
                           const float* __restrict__ freq,
                           const float* __restrict__ damp,
                           float* __restrict__ carryS,
                           float* __restrict__ carryV) {
  int n = blockIdx.x * blockDim.x + threadIdx.x;     // 0..NDIM-1
  float om = TWO_PI_F * freq[n];
  float osq = om * om;
  float dp = damp[n];
  // M = [[1-osq*dt^2, dt*(1-dp*dt)], [-osq*dt, 1-dp*dt]];  compute M^64
  float a00 = 1.f - osq * DT * DT, a01 = DT * (1.f - dp * DT);
  float a10 = -osq * DT,           a11 = 1.f - dp * DT;
#pragma unroll
  for (int i = 0; i < 6; i++) {
    float b00 = a00 * a00 + a01 * a10;
    float b01 = a00 * a01 + a01 * a11;
    float b10 = a10 * a00 + a11 * a10;
    float b11 = a10 * a01 + a11 * a11;
    a00 = b00; a01 = b01; a10 = b10; a11 = b11;
  }
  float cs = 0.f, cv = 0.f;
#pragma unroll 8
  for (int c = 0; c < CH; c++) {
    carryS[c * NDIM + n] = cs;
    carryV[c * NDIM + n] = cv;
    float ls = chunkS[c * NDIM + n];
    float lv = chunkV[c * NDIM + n];
    float ns = a00 * cs + a01 * cv + ls;
    float nv = a10 * cs + a11 * cv + lv;
    cs = ns; cv = nv;
  }
}

// ---------------- scan pass 3: replay with carries, osc + clip, fp32 out ----
__global__ void scan_pass3(const unsigned short* __restrict__ force,
                           const float* __restrict__ amp,
                           const float* __restrict__ freq,
                           const float* __restrict__ phase,
                           const float* __restrict__ damp,
                           const float* __restrict__ carryS,
                           const float* __restrict__ carryV,
                           float* __restrict__ out) {
  int gid = blockIdx.x * blockDim.x + threadIdx.x;   // gid = c*NDIM + n
  int n = gid & (NDIM - 1);
  int c = gid >> 12;
  float om = TWO_PI_F * freq[n];
  float osq = om * om;
  float dp = damp[n];
  float osc = amp[n] * sinf(om * DT + phase[n]);     // t = DT
  float s = carryS[gid], v = carryV[gid];
  const unsigned short* fp = force + (size_t)c * CL * NDIM + n;
  float* op = out + (size_t)c * CL * NDIM + n;
#pragma unroll 8
  for (int i = 0; i < CL; i++) {
    float f = bf2f(fp[(size_t)i * NDIM]);
    float a = -osq * s - dp * v + f;
    v += a * DT;
    s += v * DT;
    float o = s + osc;
    o = fminf(1.f, fmaxf(-1.f, o));
    op[(size_t)i * NDIM] = o;                        // fp32 output
  }
}

// ---------------- launch ----------------
extern "C" void kernel_launch(void* const* d_in, const int* in_sizes, int n_in,
                              void* d_out, int out_size, void* d_ws, size_t ws_size,
                              hipStream_t stream) {
  const float* x     = (const float*)d_in[0];
  const float* W     = (const float*)d_in[1];
  const float* bias  = (const float*)d_in[2];
  const float* amp   = (const float*)d_in[3];
  const float* freq  = (const float*)d_in[4];
  const float* phase = (const float*)d_in[5];
  const float* damp  = (const float*)d_in[6];

  // workspace layout (peak 64 MiB):
  //   [0,16Mi)   xbf  (later reused for chunk/carry arrays, 4 MiB)
  //   [16,32Mi)  wbf
  //   [32,64Mi)  force bf16
  unsigned short* xbf   = (unsigned short*)d_ws;
  unsigned short* wbf   = xbf + (size_t)MDIM * KDIM;
  unsigned short* force = wbf + (size_t)NDIM * KDIM;
  float* chunkS = (float*)d_ws;            // aliases xbf: safe after GEMM
  float* chunkV = chunkS + CH * NDIM;
  float* carryS = chunkV + CH * NDIM;
  float* carryV = carryS + CH * NDIM;

  cast_bf16_kernel<<<(MDIM * KDIM / 4 + 255) / 256, 256, 0, stream>>>(
      x, xbf, MDIM * KDIM / 4);
  cast_bf16_kernel<<<(NDIM * KDIM / 4 + 255) / 256, 256, 0, stream>>>(
      W, wbf, NDIM * KDIM / 4);

  dim3 gg(MDIM / 128, NDIM / 128);
  gemm_bt_kernel<<<gg, 256, 0, stream>>>(xbf, wbf, bias, force);

  scan_pass1<<<CH * NDIM / 256, 256, 0, stream>>>(force, freq, damp,
                                                  chunkS, chunkV);
  scan_pass2<<<NDIM / 256, 256, 0, stream>>>(chunkS, chunkV, freq, damp,
                                             carryS, carryV);
  scan_pass3<<<CH * NDIM / 256, 256, 0, stream>>>(
      force, amp, freq, phase, damp, carryS, carryV, (float*)d_out);
}

// Round 3
// 231.438 us; speedup vs baseline: 1.0165x; 1.0165x over previous
//
#include <hip/hip_runtime.h>
#include <hip/hip_bf16.h>
#include <math.h>

// Problem constants (B,D,N from reference)
#define MDIM 4096   // batch rows
#define KDIM 2048   // feature dim D
#define NDIM 4096   // output dim N
#define DT   0.01f
#define TWO_PI_F 6.283185307179586f
#define CH 64       // scan chunks
#define CL 64       // steps per chunk  (CH*CL == MDIM)

typedef __attribute__((ext_vector_type(8))) short bf16x8;
typedef __attribute__((ext_vector_type(4))) float f32x4;

// async global->LDS, 16B per lane (m97 pattern; dest = wave base + lane*16)
#define GLD_LDS16(g, l)                                             \
  __builtin_amdgcn_global_load_lds(                                 \
      (const __attribute__((address_space(1))) unsigned int*)(g),   \
      (__attribute__((address_space(3))) unsigned int*)(l), 16, 0, 0)

__device__ __forceinline__ unsigned short f2bf(float f) {
  unsigned int u = __float_as_uint(f);
  u += 0x7FFFu + ((u >> 16) & 1u);           // round-to-nearest-even
  return (unsigned short)(u >> 16);
}
__device__ __forceinline__ float bf2f(unsigned short u) {
  return __uint_as_float(((unsigned int)u) << 16);
}

// -------- fused cast fp32 -> bf16 for x and W (both 8M floats) --------
__global__ void cast2_bf16_kernel(const float* __restrict__ s0,
                                  unsigned short* __restrict__ d0,
                                  const float* __restrict__ s1,
                                  unsigned short* __restrict__ d1,
                                  int n4each) {
  int i = blockIdx.x * blockDim.x + threadIdx.x;
  const float4* sp;
  ushort4* dp;
  int j;
  if (i < n4each) { sp = (const float4*)s0; dp = (ushort4*)d0; j = i; }
  else            { sp = (const float4*)s1; dp = (ushort4*)d1; j = i - n4each; }
  float4 v = sp[j];
  ushort4 o;
  o.x = f2bf(v.x); o.y = f2bf(v.y); o.z = f2bf(v.z); o.w = f2bf(v.w);
  dp[j] = o;
}

// ---------------- GEMM: force = x @ W^T + b, bf16 MFMA ----------------
// A: [MDIM][KDIM] bf16 (x), Bm: [NDIM][KDIM] bf16 (W), C: [MDIM][NDIM] bf16.
// 128x128 tile, BK=32, 4 waves (2x2), 4x4 grid of 16x16x32 MFMAs per wave.
// Staging via global_load_lds width=16 (m97 structure).
__global__ __launch_bounds__(256, 2) void gemm_bt_kernel(
    const unsigned short* __restrict__ A,
    const unsigned short* __restrict__ Bm,
    const float* __restrict__ bias,
    unsigned short* __restrict__ C) {
  __shared__ __align__(16) unsigned short sA[128 * 32];
  __shared__ __align__(16) unsigned short sB[128 * 32];

  const int tid  = threadIdx.x;
  const int lane = tid & 63;
  const int wave = tid >> 6;
  const int wr = wave >> 1;        // wave row (0..1) -> 64 rows
  const int wc = wave & 1;         // wave col (0..1) -> 64 cols
  const int q  = lane >> 4;        // quad 0..3
  const int lm = lane & 15;

  const int bM = blockIdx.x * 128;
  const int bN = blockIdx.y * 128;

  f32x4 acc[4][4];
#pragma unroll
  for (int i = 0; i < 4; i++)
#pragma unroll
    for (int j = 0; j < 4; j++) acc[i][j] = (f32x4){0.f, 0.f, 0.f, 0.f};

  // staging: 128x32 bf16 tile = 8KB = 512 slots x 16B; 256 threads -> 2 slots
  const int idx0 = tid;            // slots 0..255   (rows 0..63)
  const int idx1 = tid + 256;      // slots 256..511 (rows 64..127)
  const int r0 = idx0 >> 2, c0 = (idx0 & 3) * 8;
  const int r1 = idx1 >> 2, c1 = (idx1 & 3) * 8;
  const unsigned short* gA0 = A  + (size_t)(bM + r0) * KDIM + c0;
  const unsigned short* gA1 = A  + (size_t)(bM + r1) * KDIM + c1;
  const unsigned short* gB0 = Bm + (size_t)(bN + r0) * KDIM + c0;
  const unsigned short* gB1 = Bm + (size_t)(bN + r1) * KDIM + c1;

  for (int k0 = 0; k0 < KDIM; k0 += 32) {
    __syncthreads();               // previous iter's LDS reads complete
    GLD_LDS16(gA0 + k0, &sA[idx0 * 8]);
    GLD_LDS16(gA1 + k0, &sA[idx1 * 8]);
    GLD_LDS16(gB0 + k0, &sB[idx0 * 8]);
    GLD_LDS16(gB1 + k0, &sB[idx1 * 8]);
    __syncthreads();               // vmcnt(0) drain + barrier: tile visible

    bf16x8 af[4], bfr[4];
#pragma unroll
    for (int mt = 0; mt < 4; mt++)
      af[mt]  = *(const bf16x8*)&sA[(wr * 64 + mt * 16 + lm) * 32 + q * 8];
#pragma unroll
    for (int nt = 0; nt < 4; nt++)
      bfr[nt] = *(const bf16x8*)&sB[(wc * 64 + nt * 16 + lm) * 32 + q * 8];

#pragma unroll
    for (int mt = 0; mt < 4; mt++)
#pragma unroll
      for (int nt = 0; nt < 4; nt++)
        acc[mt][nt] = __builtin_amdgcn_mfma_f32_16x16x32_bf16(
            af[mt], bfr[nt], acc[mt][nt], 0, 0, 0);
  }

  // epilogue: D layout col=lane&15, row=quad*4+reg (m89/m91-verified)
#pragma unroll
  for (int nt = 0; nt < 4; nt++) {
    const int col = bN + wc * 64 + nt * 16 + lm;
    const float bz = bias[col];
#pragma unroll
    for (int mt = 0; mt < 4; mt++) {
      const int row0 = bM + wr * 64 + mt * 16 + q * 4;
#pragma unroll
      for (int r = 0; r < 4; r++)
        C[(size_t)(row0 + r) * NDIM + col] = f2bf(acc[mt][nt][r] + bz);
    }
  }
}

// -------- scan pass 1: per-chunk partials (zero init), 4 cols/thread --------
__global__ void scan_pass1(const unsigned short* __restrict__ force,
                           const float* __restrict__ freq,
                           const float* __restrict__ damp,
                           float* __restrict__ chunkS,
                           float* __restrict__ chunkV) {
  int gid = blockIdx.x * blockDim.x + threadIdx.x;   // 0 .. CH*NDIM/4
  int n4 = gid & (NDIM / 4 - 1);
  int c  = gid >> 10;                                // / (NDIM/4)
  int n  = n4 * 4;
  float4 fr = *(const float4*)&freq[n];
  float4 dv = *(const float4*)&damp[n];
  float osq[4] = {TWO_PI_F * fr.x, TWO_PI_F * fr.y, TWO_PI_F * fr.z, TWO_PI_F * fr.w};
  float dp[4]  = {dv.x, dv.y, dv.z, dv.w};
  float s[4] = {0.f, 0.f, 0.f, 0.f}, v[4] = {0.f, 0.f, 0.f, 0.f};
#pragma unroll
  for (int j = 0; j < 4; j++) osq[j] *= osq[j];
  const unsigned short* fp = force + (size_t)c * CL * NDIM + n;
#pragma unroll 4
  for (int i = 0; i < CL; i++) {
    ushort4 fv = *(const ushort4*)&fp[(size_t)i * NDIM];
    float f[4] = {bf2f(fv.x), bf2f(fv.y), bf2f(fv.z), bf2f(fv.w)};
#pragma unroll
    for (int j = 0; j < 4; j++) {
      float a = -osq[j] * s[j] - dp[j] * v[j] + f[j];
      v[j] += a * DT;
      s[j] += v[j] * DT;
    }
  }
  *(float4*)&chunkS[c * NDIM + n] = (float4){s[0], s[1], s[2], s[3]};
  *(float4*)&chunkV[c * NDIM + n] = (float4){v[0], v[1], v[2], v[3]};
}

// ---------------- scan pass 2: sequential combine over chunks ----------------
__global__ void scan_pass2(const float* __restrict__ chunkS,
                           const float* __restrict__ chunkV,
                           const float* __restrict__ freq,
                           const float* __restrict__ damp,
                           float* __restrict__ carryS,
                           float* __restrict__ carryV) {
  int n = blockIdx.x * blockDim.x + threadIdx.x;     // 0..NDIM-1
  float om = TWO_PI_F * freq[n];
  float osq = om * om;
  float dp = damp[n];
  // M = [[1-osq*dt^2, dt*(1-dp*dt)], [-osq*dt, 1-dp*dt]];  compute M^64
  float a00 = 1.f - osq * DT * DT, a01 = DT * (1.f - dp * DT);
  float a10 = -osq * DT,           a11 = 1.f - dp * DT;
#pragma unroll
  for (int i = 0; i < 6; i++) {
    float b00 = a00 * a00 + a01 * a10;
    float b01 = a00 * a01 + a01 * a11;
    float b10 = a10 * a00 + a11 * a10;
    float b11 = a10 * a01 + a11 * a11;
    a00 = b00; a01 = b01; a10 = b10; a11 = b11;
  }
  float cs = 0.f, cv = 0.f;
#pragma unroll 8
  for (int c = 0; c < CH; c++) {
    carryS[c * NDIM + n] = cs;
    carryV[c * NDIM + n] = cv;
    float ls = chunkS[c * NDIM + n];
    float lv = chunkV[c * NDIM + n];
    float ns = a00 * cs + a01 * cv + ls;
    float nv = a10 * cs + a11 * cv + lv;
    cs = ns; cv = nv;
  }
}

// -------- scan pass 3: replay with carries, osc+clip, fp32 out, 4 cols ------
__global__ void scan_pass3(const unsigned short* __restrict__ force,
                           const float* __restrict__ amp,
                           const float* __restrict__ freq,
                           const float* __restrict__ phase,
                           const float* __restrict__ damp,
                           const float* __restrict__ carryS,
                           const float* __restrict__ carryV,
                           float* __restrict__ out) {
  int gid = blockIdx.x * blockDim.x + threadIdx.x;   // 0 .. CH*NDIM/4
  int n4 = gid & (NDIM / 4 - 1);
  int c  = gid >> 10;
  int n  = n4 * 4;
  float4 fr = *(const float4*)&freq[n];
  float4 dv = *(const float4*)&damp[n];
  float4 am = *(const float4*)&amp[n];
  float4 ph = *(const float4*)&phase[n];
  float om[4] = {TWO_PI_F * fr.x, TWO_PI_F * fr.y, TWO_PI_F * fr.z, TWO_PI_F * fr.w};
  float dp[4] = {dv.x, dv.y, dv.z, dv.w};
  float osq[4], osc[4], s[4], v[4];
  float amv[4] = {am.x, am.y, am.z, am.w};
  float phv[4] = {ph.x, ph.y, ph.z, ph.w};
#pragma unroll
  for (int j = 0; j < 4; j++) {
    osq[j] = om[j] * om[j];
    osc[j] = amv[j] * sinf(om[j] * DT + phv[j]);     // t = DT
  }
  float4 csv = *(const float4*)&carryS[c * NDIM + n];
  float4 cvv = *(const float4*)&carryV[c * NDIM + n];
  s[0] = csv.x; s[1] = csv.y; s[2] = csv.z; s[3] = csv.w;
  v[0] = cvv.x; v[1] = cvv.y; v[2] = cvv.z; v[3] = cvv.w;
  const unsigned short* fp = force + (size_t)c * CL * NDIM + n;
  float* op = out + (size_t)c * CL * NDIM + n;
#pragma unroll 4
  for (int i = 0; i < CL; i++) {
    ushort4 fv = *(const ushort4*)&fp[(size_t)i * NDIM];
    float f[4] = {bf2f(fv.x), bf2f(fv.y), bf2f(fv.z), bf2f(fv.w)};
    float o[4];
#pragma unroll
    for (int j = 0; j < 4; j++) {
      float a = -osq[j] * s[j] - dp[j] * v[j] + f[j];
      v[j] += a * DT;
      s[j] += v[j] * DT;
      o[j] = fminf(1.f, fmaxf(-1.f, s[j] + osc[j]));
    }
    *(float4*)&op[(size_t)i * NDIM] = (float4){o[0], o[1], o[2], o[3]};
  }
}

// ---------------- launch ----------------
extern "C" void kernel_launch(void* const* d_in, const int* in_sizes, int n_in,
                              void* d_out, int out_size, void* d_ws, size_t ws_size,
                              hipStream_t stream) {
  const float* x     = (const float*)d_in[0];
  const float* W     = (const float*)d_in[1];
  const float* bias  = (const float*)d_in[2];
  const float* amp   = (const float*)d_in[3];
  const float* freq  = (const float*)d_in[4];
  const float* phase = (const float*)d_in[5];
  const float* damp  = (const float*)d_in[6];

  // workspace layout (peak 64 MiB):
  //   [0,16Mi)   xbf  (later reused for chunk/carry arrays, 4 MiB)
  //   [16,32Mi)  wbf
  //   [32,64Mi)  force bf16
  unsigned short* xbf   = (unsigned short*)d_ws;
  unsigned short* wbf   = xbf + (size_t)MDIM * KDIM;
  unsigned short* force = wbf + (size_t)NDIM * KDIM;
  float* chunkS = (float*)d_ws;            // aliases xbf: safe after GEMM
  float* chunkV = chunkS + CH * NDIM;
  float* carryS = chunkV + CH * NDIM;
  float* carryV = carryS + CH * NDIM;

  const int n4each = MDIM * KDIM / 4;      // == NDIM*KDIM/4 (both 8M floats)
  cast2_bf16_kernel<<<(2 * n4each + 255) / 256, 256, 0, stream>>>(
      x, xbf, W, wbf, n4each);

  dim3 gg(MDIM / 128, NDIM / 128);
  gemm_bt_kernel<<<gg, 256, 0, stream>>>(xbf, wbf, bias, force);

  scan_pass1<<<CH * NDIM / 4 / 256, 256, 0, stream>>>(force, freq, damp,
                                                      chunkS, chunkV);
  scan_pass2<<<NDIM / 256, 256, 0, stream>>>(chunkS, chunkV, freq, damp,
                                             carryS, carryV);
  scan_pass3<<<CH * NDIM / 4 / 256, 256, 0, stream>>>(
      force, amp, freq, phase, damp, carryS, carryV, (float*)d_out);
}